// Round 12
// baseline (363.019 us; speedup 1.0000x reference)
//
#include <hip/hip_runtime.h>
#include <hip/hip_bf16.h>
#include <hip/hip_cooperative_groups.h>

namespace cg = cooperative_groups;

typedef unsigned short u16;
typedef __bf16 bf16x8 __attribute__((ext_vector_type(8)));
typedef float f32x4 __attribute__((ext_vector_type(4)));

typedef const __attribute__((address_space(1))) void gv_t;
typedef __attribute__((address_space(3))) void lv_t;

#define NN 2048
#define DD 1024
#define SS 49
#define CC 1000
#define CP 1024

#define BK 64
#define KK DD
#define NT (KK / BK)   // 16 K-steps

__device__ inline u16 f2bf(float f) {
    __hip_bfloat16 h = __float2bfloat16(f);
    union { __hip_bfloat16 h; u16 u; } cv; cv.h = h; return cv.u;
}

// ---- 64x64 MFMA GEMM core (r3/r6 2-phase dbuf, 32KB window of smem) --------
__device__ __forceinline__ void gemm64_core(const u16* __restrict__ A,
                                            const u16* __restrict__ Bt,
                                            int m0, int n0, char* smem,
                                            f32x4 acc[2][2], int tid) {
    char* As = smem;            // [2][8192]
    char* Bs = smem + 16384;    // [2][8192]
    const int lane = tid & 63;
    const int wr = (tid >> 6) >> 1, wc = (tid >> 6) & 1;
    const int r16 = lane & 15, hk = lane >> 4;
    const char* Ab = (const char*)A;
    const char* Bb = (const char*)Bt;

    auto stage = [&](int buf, int k0) {
        #pragma unroll
        for (int j = 0; j < 2; j++) {
            const int c = j * 256 + tid;
            const int row = c >> 3, slot = c & 7;
            const int goff = ((slot ^ (row & 7)) << 4);
            __builtin_amdgcn_global_load_lds(
                (gv_t*)(Ab + ((size_t)(m0 + row) * KK + k0) * 2 + goff),
                (lv_t*)(As + buf * 8192 + c * 16), 16, 0, 0);
            __builtin_amdgcn_global_load_lds(
                (gv_t*)(Bb + ((size_t)(n0 + row) * KK + k0) * 2 + goff),
                (lv_t*)(Bs + buf * 8192 + c * 16), 16, 0, 0);
        }
    };

    stage(0, 0);
    __syncthreads();
    int cur = 0;
    for (int t = 0; t < NT; ++t) {
        if (t + 1 < NT) stage(cur ^ 1, (t + 1) * BK);
        bf16x8 a[2][2], b[2][2];
        #pragma unroll
        for (int mi = 0; mi < 2; mi++) {
            const int row = wr * 32 + mi * 16 + r16;
            #pragma unroll
            for (int kk2 = 0; kk2 < 2; kk2++) {
                const int g = kk2 * 4 + hk;
                a[mi][kk2] = *(const bf16x8*)(As + cur * 8192 + row * 128 + ((g ^ (row & 7)) << 4));
            }
        }
        #pragma unroll
        for (int ni = 0; ni < 2; ni++) {
            const int row = wc * 32 + ni * 16 + r16;
            #pragma unroll
            for (int kk2 = 0; kk2 < 2; kk2++) {
                const int g = kk2 * 4 + hk;
                b[ni][kk2] = *(const bf16x8*)(Bs + cur * 8192 + row * 128 + ((g ^ (row & 7)) << 4));
            }
        }
        #pragma unroll
        for (int kk2 = 0; kk2 < 2; kk2++)
            #pragma unroll
            for (int mi = 0; mi < 2; mi++)
                #pragma unroll
                for (int ni = 0; ni < 2; ni++)
                    acc[mi][ni] = __builtin_amdgcn_mfma_f32_16x16x32_bf16(
                        a[mi][kk2], b[ni][kk2], acc[mi][ni], 0, 0, 0);
        __syncthreads();
        cur ^= 1;
    }
}

// ---- phase bodies ----------------------------------------------------------

// prep tile t in [0,256): q tile (coalesced P^T via LDS transpose) + mu chunk
__device__ __forceinline__ void prep_tile(int t, const float* __restrict__ P,
                                          const float* __restrict__ mu,
                                          u16* __restrict__ q,
                                          u16* __restrict__ mu_bf,
                                          char* smem, int tid) {
    float (*t1)[65] = (float(*)[65])smem;            // 64*65*4 = 16640
    float (*t2)[65] = (float(*)[65])(smem + 16640);  // +16640 = 33280 <= 50176
    const int br = t >> 4, bc = t & 15;
    const int br64 = br * 64, bc64 = bc * 64;

    #pragma unroll
    for (int it = 0; it < 16; it++) {
        const int idx = it * 256 + tid;
        const int row = idx >> 6, col = idx & 63;
        t1[row][col] = P[(size_t)(br64 + row) * DD + bc64 + col];
        t2[row][col] = P[(size_t)(bc64 + row) * DD + br64 + col];
    }
    __syncthreads();
    #pragma unroll
    for (int it = 0; it < 16; it++) {
        const int idx = it * 256 + tid;
        const int row = idx >> 6, col = idx & 63;
        q[(size_t)(br64 + row) * DD + bc64 + col] = f2bf(t1[row][col] + t2[col][row]);
    }
    const size_t base = (size_t)t * 4096;
    #pragma unroll
    for (int it = 0; it < 16; it++) {
        const size_t j = base + it * 256 + tid;
        const int r = (int)(j >> 10);
        mu_bf[j] = f2bf(r < CC ? mu[j] : 0.f);
    }
    __syncthreads();   // smem reusable by next grid-stride iteration
}

// pool unit u in [0,8192): z for 256 (n,d) rows
__device__ __forceinline__ void pool_unit(int u, const float* __restrict__ x,
                                          float* __restrict__ zf,
                                          u16* __restrict__ zb,
                                          char* smem, int tid) {
    float* lds = (float*)smem;                       // 12544 floats = 50176 B
    const size_t base = (size_t)u * (256 * SS);
    const float4* src = (const float4*)(x + base);
    float4* dst = (float4*)lds;
    #pragma unroll
    for (int i = 0; i < 13; i++) {
        int idx = i * 256 + tid;
        if (idx < (256 * SS) / 4) dst[idx] = src[idx];
    }
    __syncthreads();
    const float* r = lds + tid * SS;
    float s = 0.f;
    #pragma unroll
    for (int j = 0; j < SS; j++) s += r[j];
    s *= (1.f / 49.f);
    size_t o = (size_t)u * 256 + tid;
    zf[o] = s;
    zb[o] = f2bf(s);
    __syncthreads();   // protect smem for next unit
}

// muQ tile t in [0,256): b_bf tile + qmuh atomics
__device__ __forceinline__ void muq_tile(int t, const u16* __restrict__ mu_bf,
                                         const u16* __restrict__ q,
                                         const float* __restrict__ mu,
                                         u16* __restrict__ b_bf,
                                         float* __restrict__ qmuh,
                                         char* smem, int tid) {
    const int m0 = (t >> 4) * 64, n0 = (t & 15) * 64;
    f32x4 acc[2][2] = {};
    gemm64_core(mu_bf, q, m0, n0, smem, acc, tid);

    const int lane = tid & 63;
    const int wr = (tid >> 6) >> 1, wc = (tid >> 6) & 1;
    const int cr = (lane >> 4) * 4, cc2 = lane & 15;
    #pragma unroll
    for (int mi = 0; mi < 2; mi++) {
        const int gr0 = m0 + wr * 32 + mi * 16 + cr;
        #pragma unroll
        for (int r = 0; r < 4; r++) {
            const int row = gr0 + r;
            float v = 0.f;
            #pragma unroll
            for (int ni = 0; ni < 2; ni++) {
                const int gc = n0 + wc * 32 + ni * 16 + cc2;
                float av = acc[mi][ni][r];
                float sv = (row < CC) ? mu[(size_t)row * DD + gc] : 0.f;
                v += av * sv;
                b_bf[(size_t)row * DD + gc] = f2bf(av);
            }
            #pragma unroll
            for (int m = 1; m < 16; m <<= 1) v += __shfl_xor(v, m);
            if (cc2 == 0) atomicAdd(qmuh + row, 0.25f * v);
        }
    }
}

// fused zQ-diag + score tile t in [0,512): dual-B GEMM (r11 body)
__device__ __forceinline__ void zscore_tile(int t, const u16* __restrict__ z_bf,
                                            const u16* __restrict__ q,
                                            const u16* __restrict__ b_bf,
                                            const float* __restrict__ zf,
                                            float* __restrict__ qzh,
                                            const float* __restrict__ qmuh,
                                            float* __restrict__ out,
                                            char* smem, int tid) {
    const int m0 = (t >> 4) * 64, n0 = (t & 15) * 64;
    const int lane = tid & 63;
    const int wr = (tid >> 6) >> 1, wc = (tid >> 6) & 1;
    const int r16 = lane & 15, hk = lane >> 4;
    char* As = smem;
    char* Bq = smem + 16384;
    char* Bb = smem + 32768;   // 49152 <= 50176
    const char* Ap = (const char*)z_bf;
    const char* Qp = (const char*)q;
    const char* Bp = (const char*)b_bf;

    f32x4 accS[2][2] = {};
    f32x4 accZ[2][2] = {};

    auto stage = [&](int buf, int k0) {
        #pragma unroll
        for (int j = 0; j < 2; j++) {
            const int c = j * 256 + tid;
            const int row = c >> 3, slot = c & 7;
            const int goff = ((slot ^ (row & 7)) << 4);
            const size_t ao = ((size_t)(m0 + row) * KK + k0) * 2 + goff;
            const size_t bo = ((size_t)(n0 + row) * KK + k0) * 2 + goff;
            __builtin_amdgcn_global_load_lds((gv_t*)(Ap + ao),
                (lv_t*)(As + buf * 8192 + c * 16), 16, 0, 0);
            __builtin_amdgcn_global_load_lds((gv_t*)(Qp + bo),
                (lv_t*)(Bq + buf * 8192 + c * 16), 16, 0, 0);
            __builtin_amdgcn_global_load_lds((gv_t*)(Bp + bo),
                (lv_t*)(Bb + buf * 8192 + c * 16), 16, 0, 0);
        }
    };

    stage(0, 0);
    __syncthreads();
    int cur = 0;
    for (int kt = 0; kt < NT; ++kt) {
        if (kt + 1 < NT) stage(cur ^ 1, (kt + 1) * BK);
        bf16x8 a[2][2], bq[2][2], bb[2][2];
        #pragma unroll
        for (int mi = 0; mi < 2; mi++) {
            const int row = wr * 32 + mi * 16 + r16;
            #pragma unroll
            for (int kk2 = 0; kk2 < 2; kk2++) {
                const int g = kk2 * 4 + hk;
                a[mi][kk2] = *(const bf16x8*)(As + cur * 8192 + row * 128 + ((g ^ (row & 7)) << 4));
            }
        }
        #pragma unroll
        for (int ni = 0; ni < 2; ni++) {
            const int row = wc * 32 + ni * 16 + r16;
            #pragma unroll
            for (int kk2 = 0; kk2 < 2; kk2++) {
                const int g = kk2 * 4 + hk;
                const int off = row * 128 + ((g ^ (row & 7)) << 4);
                bq[ni][kk2] = *(const bf16x8*)(Bq + cur * 8192 + off);
                bb[ni][kk2] = *(const bf16x8*)(Bb + cur * 8192 + off);
            }
        }
        #pragma unroll
        for (int kk2 = 0; kk2 < 2; kk2++)
            #pragma unroll
            for (int mi = 0; mi < 2; mi++)
                #pragma unroll
                for (int ni = 0; ni < 2; ni++) {
                    accS[mi][ni] = __builtin_amdgcn_mfma_f32_16x16x32_bf16(
                        a[mi][kk2], bb[ni][kk2], accS[mi][ni], 0, 0, 0);
                    accZ[mi][ni] = __builtin_amdgcn_mfma_f32_16x16x32_bf16(
                        a[mi][kk2], bq[ni][kk2], accZ[mi][ni], 0, 0, 0);
                }
        __syncthreads();
        cur ^= 1;
    }

    const int cr = hk * 4, cc2 = r16;
    #pragma unroll
    for (int mi = 0; mi < 2; mi++) {
        const int gr0 = m0 + wr * 32 + mi * 16 + cr;
        #pragma unroll
        for (int r = 0; r < 4; r++) {
            const int row = gr0 + r;
            float v = 0.f;
            #pragma unroll
            for (int ni = 0; ni < 2; ni++) {
                const int gc = n0 + wc * 32 + ni * 16 + cc2;
                v += accZ[mi][ni][r] * zf[(size_t)row * DD + gc];
            }
            #pragma unroll
            for (int m = 1; m < 16; m <<= 1) v += __shfl_xor(v, m);
            if (cc2 == 0) atomicAdd(qzh + row, 0.25f * v);
        }
    }
    #pragma unroll
    for (int mi = 0; mi < 2; mi++) {
        #pragma unroll
        for (int ni = 0; ni < 2; ni++) {
            const int gr = m0 + wr * 32 + mi * 16 + cr;
            const int gc = n0 + wc * 32 + ni * 16 + cc2;
            if (gc < CC) {
                const float qm = qmuh[gc];
                #pragma unroll
                for (int r = 0; r < 4; r++)
                    out[(size_t)(gr + r) * CC + gc] =
                        0.5f * accS[mi][ni][r] - qm;
            }
        }
    }
}

// ---- the cooperative mega-kernel: 4 phases, 3 grid syncs -------------------
__global__ __launch_bounds__(256) void mega_k(const float* __restrict__ x,
                                              const float* __restrict__ P,
                                              const float* __restrict__ mu,
                                              u16* __restrict__ q,
                                              u16* __restrict__ mu_bf,
                                              u16* __restrict__ b_bf,
                                              u16* __restrict__ z_bf,
                                              float* __restrict__ zf,
                                              float* __restrict__ qzh,
                                              float* __restrict__ qmuh,
                                              float* __restrict__ out) {
    cg::grid_group grid = cg::this_grid();
    __shared__ char smem[50176];
    const int tid = threadIdx.x, bid = blockIdx.x, NB = gridDim.x;

    // Phase A: prep (256 tiles, grid-stride) + zero qzh/qmuh
    {
        const int g = bid * 256 + tid;
        if (g < NN) qzh[g]  = 0.f;
        if (g < CP) qmuh[g] = 0.f;
    }
    for (int t = bid; t < 256; t += NB)
        prep_tile(t, P, mu, q, mu_bf, smem, tid);
    __threadfence();
    grid.sync();

    // Phase B: muQ (items 0..255, lands on first blocks -> hidden) + pool
    for (int i = bid; i < 256 + 8192; i += NB) {
        if (i < 256) muq_tile(i, mu_bf, q, mu, b_bf, qmuh, smem, tid);
        else         pool_unit(i - 256, x, zf, z_bf, smem, tid);
    }
    __threadfence();
    grid.sync();

    // Phase C: fused zQ-diag + score (512 dual-B tiles)
    for (int t = bid; t < 512; t += NB)
        zscore_tile(t, z_bf, q, b_bf, zf, qzh, qmuh, out, smem, tid);
    __threadfence();
    grid.sync();

    // Phase D: out[n,:] -= qzh[n] in place
    for (int n = bid; n < NN; n += NB) {
        if (tid < 250) {
            const float qz = qzh[n];
            float4* p = (float4*)(out + (size_t)n * CC + tid * 4);
            float4 v = *p;
            v.x -= qz; v.y -= qz; v.z -= qz; v.w -= qz;
            *p = v;
        }
    }
}

extern "C" void kernel_launch(void* const* d_in, const int* in_sizes, int n_in,
                              void* d_out, int out_size, void* d_ws, size_t ws_size,
                              hipStream_t stream) {
    const float* x  = (const float*)d_in[0];   // [N, D, S]
    const float* mu = (const float*)d_in[1];   // [C, D]
    const float* P  = (const float*)d_in[2];   // [D, D]
    float* out = (float*)d_out;                // [N, C]

    // workspace carve (~18.3 MB)
    char* w = (char*)d_ws;
    u16*   q_bf  = (u16*)w;   w += (size_t)DD * DD * 2;   // 2 MB
    u16*   mu_bf = (u16*)w;   w += (size_t)CP * DD * 2;   // 2 MB
    u16*   b_bf  = (u16*)w;   w += (size_t)CP * DD * 2;   // 2 MB
    u16*   z_bf  = (u16*)w;   w += (size_t)NN * DD * 2;   // 4 MB
    float* zf    = (float*)w; w += (size_t)NN * DD * 4;   // 8 MB
    float* qzh   = (float*)w; w += (size_t)NN * 4;
    float* qmuh  = (float*)w;

    int occ = 0;
    if (hipOccupancyMaxActiveBlocksPerMultiprocessor(&occ, (const void*)mega_k,
                                                     256, 0) != hipSuccess || occ < 1)
        occ = 1;
    int NB = occ * 256;            // 256 CUs; LDS 50176B -> expect occ=3 -> 768
    if (NB > 768) NB = 768;

    void* args[] = { (void*)&x, (void*)&P, (void*)&mu, (void*)&q_bf,
                     (void*)&mu_bf, (void*)&b_bf, (void*)&z_bf, (void*)&zf,
                     (void*)&qzh, (void*)&qmuh, (void*)&out };
    hipLaunchCooperativeKernel((const void*)mega_k, dim3(NB), dim3(256),
                               args, 0, stream);
}

// Round 13
// 276.937 us; speedup vs baseline: 1.3108x; 1.3108x over previous
//
#include <hip/hip_runtime.h>
#include <hip/hip_bf16.h>

typedef unsigned short u16;
typedef __bf16 bf16x8 __attribute__((ext_vector_type(8)));
typedef float f32x4 __attribute__((ext_vector_type(4)));

typedef const __attribute__((address_space(1))) void gv_t;
typedef __attribute__((address_space(3))) void lv_t;

#define NN 2048
#define DD 1024
#define SS 49
#define CC 1000
#define CP 1024

#define BK 64
#define KK DD
#define NT (KK / BK)   // 16 K-steps

__device__ inline u16 f2bf(float f) {
    __hip_bfloat16 h = __float2bfloat16(f);
    union { __hip_bfloat16 h; u16 u; } cv; cv.h = h; return cv.u;
}

// ---- 64x64 MFMA GEMM core: 2-phase double-buffer, 32KB LDS (r3/r6 core) ----
__device__ __forceinline__ void gemm64_core(const u16* __restrict__ A,
                                            const u16* __restrict__ Bt,
                                            int m0, int n0, char* smem,
                                            f32x4 acc[2][2], int tid) {
    char* As = smem;            // [2][8192]
    char* Bs = smem + 16384;    // [2][8192]
    const int lane = tid & 63;
    const int wr = (tid >> 6) >> 1, wc = (tid >> 6) & 1;
    const int r16 = lane & 15, hk = lane >> 4;
    const char* Ab = (const char*)A;
    const char* Bb = (const char*)Bt;

    auto stage = [&](int buf, int k0) {
        #pragma unroll
        for (int j = 0; j < 2; j++) {
            const int c = j * 256 + tid;
            const int row = c >> 3, slot = c & 7;
            const int goff = ((slot ^ (row & 7)) << 4);
            __builtin_amdgcn_global_load_lds(
                (gv_t*)(Ab + ((size_t)(m0 + row) * KK + k0) * 2 + goff),
                (lv_t*)(As + buf * 8192 + c * 16), 16, 0, 0);
            __builtin_amdgcn_global_load_lds(
                (gv_t*)(Bb + ((size_t)(n0 + row) * KK + k0) * 2 + goff),
                (lv_t*)(Bs + buf * 8192 + c * 16), 16, 0, 0);
        }
    };

    stage(0, 0);
    __syncthreads();
    int cur = 0;
    for (int t = 0; t < NT; ++t) {
        if (t + 1 < NT) stage(cur ^ 1, (t + 1) * BK);
        bf16x8 a[2][2], b[2][2];
        #pragma unroll
        for (int mi = 0; mi < 2; mi++) {
            const int row = wr * 32 + mi * 16 + r16;
            #pragma unroll
            for (int kk2 = 0; kk2 < 2; kk2++) {
                const int g = kk2 * 4 + hk;
                a[mi][kk2] = *(const bf16x8*)(As + cur * 8192 + row * 128 + ((g ^ (row & 7)) << 4));
            }
        }
        #pragma unroll
        for (int ni = 0; ni < 2; ni++) {
            const int row = wc * 32 + ni * 16 + r16;
            #pragma unroll
            for (int kk2 = 0; kk2 < 2; kk2++) {
                const int g = kk2 * 4 + hk;
                b[ni][kk2] = *(const bf16x8*)(Bs + cur * 8192 + row * 128 + ((g ^ (row & 7)) << 4));
            }
        }
        #pragma unroll
        for (int kk2 = 0; kk2 < 2; kk2++)
            #pragma unroll
            for (int mi = 0; mi < 2; mi++)
                #pragma unroll
                for (int ni = 0; ni < 2; ni++)
                    acc[mi][ni] = __builtin_amdgcn_mfma_f32_16x16x32_bf16(
                        a[mi][kk2], b[ni][kk2], acc[mi][ni], 0, 0, 0);
        __syncthreads();
        cur ^= 1;
    }
}

// ---- L0: prep via LDS tile transpose (r10) ---------------------------------
__global__ __launch_bounds__(256) void prep_k(const float* __restrict__ P,
                                              const float* __restrict__ mu,
                                              u16* __restrict__ q,
                                              u16* __restrict__ mu_bf,
                                              float* __restrict__ qzh,
                                              float* __restrict__ qmuh) {
    __shared__ float t1[64][65];
    __shared__ float t2[64][65];
    const int tid = threadIdx.x, bid = blockIdx.x;
    const int br = bid >> 4, bc = bid & 15;
    const int br64 = br * 64, bc64 = bc * 64;

    #pragma unroll
    for (int it = 0; it < 16; it++) {
        const int idx = it * 256 + tid;
        const int row = idx >> 6, col = idx & 63;
        t1[row][col] = P[(size_t)(br64 + row) * DD + bc64 + col];
        t2[row][col] = P[(size_t)(bc64 + row) * DD + br64 + col];
    }
    __syncthreads();
    #pragma unroll
    for (int it = 0; it < 16; it++) {
        const int idx = it * 256 + tid;
        const int row = idx >> 6, col = idx & 63;
        q[(size_t)(br64 + row) * DD + bc64 + col] = f2bf(t1[row][col] + t2[col][row]);
    }

    const size_t base = (size_t)bid * 4096;
    #pragma unroll
    for (int it = 0; it < 16; it++) {
        const size_t j = base + it * 256 + tid;
        const int r = (int)(j >> 10);
        mu_bf[j] = f2bf(r < CC ? mu[j] : 0.f);
    }
    const int g = bid * 256 + tid;
    if (g < NN) qzh[g]  = 0.f;
    if (g < CP) qmuh[g] = 0.f;
}

// ---- L1: muQ GEMM (256 blocks, first) + pool (8192 blocks) — r10 verbatim --
__global__ __launch_bounds__(256) void pool_muq_k(const float* __restrict__ x,
                                                  const u16* __restrict__ q,
                                                  const u16* __restrict__ mu_bf,
                                                  const float* __restrict__ mu,
                                                  u16* __restrict__ b_bf,
                                                  float* __restrict__ qmuh,
                                                  float* __restrict__ zf,
                                                  u16* __restrict__ zb) {
    __shared__ char smem[50176];   // pool: float[12544]; gemm: 2x16KB dbuf
    const int tid = threadIdx.x;
    const int bid = blockIdx.x;

    if (bid >= 256) {
        const int u = bid - 256;
        float* lds = (float*)smem;
        const size_t base = (size_t)u * (256 * SS);
        const float4* src = (const float4*)(x + base);
        float4* dst = (float4*)lds;
        #pragma unroll
        for (int i = 0; i < 13; i++) {
            int idx = i * 256 + tid;
            if (idx < (256 * SS) / 4) dst[idx] = src[idx];
        }
        __syncthreads();
        const float* r = lds + tid * SS;
        float s = 0.f;
        #pragma unroll
        for (int j = 0; j < SS; j++) s += r[j];
        s *= (1.f / 49.f);
        size_t o = (size_t)u * 256 + tid;
        zf[o] = s;
        zb[o] = f2bf(s);
        return;
    }

    const int m0 = (bid >> 4) * 64, n0 = (bid & 15) * 64;
    f32x4 acc[2][2] = {};
    gemm64_core(mu_bf, q, m0, n0, smem, acc, tid);

    const int lane = tid & 63;
    const int wr = (tid >> 6) >> 1, wc = (tid >> 6) & 1;
    const int cr = (lane >> 4) * 4, cc2 = lane & 15;
    #pragma unroll
    for (int mi = 0; mi < 2; mi++) {
        const int gr0 = m0 + wr * 32 + mi * 16 + cr;
        #pragma unroll
        for (int r = 0; r < 4; r++) {
            const int row = gr0 + r;
            float v = 0.f;
            #pragma unroll
            for (int ni = 0; ni < 2; ni++) {
                const int gc = n0 + wc * 32 + ni * 16 + cc2;
                float av = acc[mi][ni][r];
                float sv = (row < CC) ? mu[(size_t)row * DD + gc] : 0.f;
                v += av * sv;
                b_bf[(size_t)row * DD + gc] = f2bf(av);
            }
            #pragma unroll
            for (int m = 1; m < 16; m <<= 1) v += __shfl_xor(v, m);
            if (cc2 == 0) atomicAdd(qmuh + row, 0.25f * v);
        }
    }
}

// ---- MEASUREMENT PROBE: pool-only (idempotent rewrite of zf/z_bf). ----------
// Launched 2 extra times: dur_total = dur_r10 + 2*P_pool, solving P_pool.
// No atomics, deterministic values -> correctness unaffected.
__global__ __launch_bounds__(256) void pool_only_k(const float* __restrict__ x,
                                                   float* __restrict__ zf,
                                                   u16* __restrict__ zb) {
    __shared__ float lds[12544];
    const int tid = threadIdx.x;
    const int u = blockIdx.x;
    const size_t base = (size_t)u * (256 * SS);
    const float4* src = (const float4*)(x + base);
    float4* dst = (float4*)lds;
    #pragma unroll
    for (int i = 0; i < 13; i++) {
        int idx = i * 256 + tid;
        if (idx < (256 * SS) / 4) dst[idx] = src[idx];
    }
    __syncthreads();
    const float* r = lds + tid * SS;
    float s = 0.f;
    #pragma unroll
    for (int j = 0; j < SS; j++) s += r[j];
    s *= (1.f / 49.f);
    size_t o = (size_t)u * 256 + tid;
    zf[o] = s;
    zb[o] = f2bf(s);
}

// ---- L2: zQ-diag (bid<512) + score-partial (512) — r10 verbatim ------------
__global__ __launch_bounds__(256) void zgemm_k(const u16* __restrict__ z_bf,
                                               const u16* __restrict__ q,
                                               const u16* __restrict__ b_bf,
                                               const float* __restrict__ zf,
                                               float* __restrict__ qzh,
                                               const float* __restrict__ qmuh,
                                               float* __restrict__ out) {
    __shared__ char smem[32768];
    const int tid = threadIdx.x;
    const int bid = blockIdx.x;
    const int lane = tid & 63;
    const int wr = (tid >> 6) >> 1, wc = (tid >> 6) & 1;
    const int cr = (lane >> 4) * 4, cc2 = lane & 15;

    if (bid < 512) {
        const int m0 = (bid >> 4) * 64, n0 = (bid & 15) * 64;
        f32x4 acc[2][2] = {};
        gemm64_core(z_bf, q, m0, n0, smem, acc, tid);
        #pragma unroll
        for (int mi = 0; mi < 2; mi++) {
            const int gr0 = m0 + wr * 32 + mi * 16 + cr;
            #pragma unroll
            for (int r = 0; r < 4; r++) {
                const int row = gr0 + r;
                float v = 0.f;
                #pragma unroll
                for (int ni = 0; ni < 2; ni++) {
                    const int gc = n0 + wc * 32 + ni * 16 + cc2;
                    v += acc[mi][ni][r] * zf[(size_t)row * DD + gc];
                }
                #pragma unroll
                for (int m = 1; m < 16; m <<= 1) v += __shfl_xor(v, m);
                if (cc2 == 0) atomicAdd(qzh + row, 0.25f * v);
            }
        }
    } else {
        const int i = bid - 512;
        const int m0 = (i >> 4) * 64, n0 = (i & 15) * 64;
        f32x4 acc[2][2] = {};
        gemm64_core(z_bf, b_bf, m0, n0, smem, acc, tid);
        #pragma unroll
        for (int mi = 0; mi < 2; mi++) {
            #pragma unroll
            for (int ni = 0; ni < 2; ni++) {
                const int gr = m0 + wr * 32 + mi * 16 + cr;
                const int gc = n0 + wc * 32 + ni * 16 + cc2;
                if (gc < CC) {
                    const float qm = qmuh[gc];
                    #pragma unroll
                    for (int r = 0; r < 4; r++)
                        out[(size_t)(gr + r) * CC + gc] =
                            0.5f * acc[mi][ni][r] - qm;
                }
            }
        }
    }
}

// ---- L3: in-place fixup out[n,c] -= qzh[n] ---------------------------------
__global__ __launch_bounds__(256) void fixup_k(float* __restrict__ out,
                                               const float* __restrict__ qzh) {
    const int n = blockIdx.x, tid = threadIdx.x;
    if (tid >= 250) return;
    const float qz = qzh[n];
    float4* p = (float4*)(out + (size_t)n * CC + tid * 4);
    float4 v = *p;
    v.x -= qz; v.y -= qz; v.z -= qz; v.w -= qz;
    *p = v;
}

extern "C" void kernel_launch(void* const* d_in, const int* in_sizes, int n_in,
                              void* d_out, int out_size, void* d_ws, size_t ws_size,
                              hipStream_t stream) {
    const float* x  = (const float*)d_in[0];   // [N, D, S]
    const float* mu = (const float*)d_in[1];   // [C, D]
    const float* P  = (const float*)d_in[2];   // [D, D]
    float* out = (float*)d_out;                // [N, C]

    // workspace carve (~18.3 MB)
    char* w = (char*)d_ws;
    u16*   q_bf  = (u16*)w;   w += (size_t)DD * DD * 2;   // 2 MB
    u16*   mu_bf = (u16*)w;   w += (size_t)CP * DD * 2;   // 2 MB
    u16*   b_bf  = (u16*)w;   w += (size_t)CP * DD * 2;   // 2 MB
    u16*   z_bf  = (u16*)w;   w += (size_t)NN * DD * 2;   // 4 MB
    float* zf    = (float*)w; w += (size_t)NN * DD * 4;   // 8 MB
    float* qzh   = (float*)w; w += (size_t)NN * 4;
    float* qmuh  = (float*)w;

    // ---- r10 pipeline, verbatim ----
    prep_k<<<256, 256, 0, stream>>>(P, mu, q_bf, mu_bf, qzh, qmuh);
    pool_muq_k<<<256 + (NN * DD) / 256, 256, 0, stream>>>(
        x, q_bf, mu_bf, mu, b_bf, qmuh, zf, z_bf);
    // ---- measurement probe: 2 extra idempotent pool passes ----
    pool_only_k<<<(NN * DD) / 256, 256, 0, stream>>>(x, zf, z_bf);
    pool_only_k<<<(NN * DD) / 256, 256, 0, stream>>>(x, zf, z_bf);
    // ---- rest of r10 pipeline ----
    zgemm_k<<<1024, 256, 0, stream>>>(z_bf, q_bf, b_bf, zf, qzh, qmuh, out);
    fixup_k<<<NN, 256, 0, stream>>>(out, qzh);
}

// Round 14
// 118.524 us; speedup vs baseline: 3.0628x; 2.3365x over previous
//
#include <hip/hip_runtime.h>
#include <hip/hip_bf16.h>

typedef unsigned short u16;
typedef __bf16 bf16x8 __attribute__((ext_vector_type(8)));
typedef float f32x4 __attribute__((ext_vector_type(4)));

typedef const __attribute__((address_space(1))) void gv_t;
typedef __attribute__((address_space(3))) void lv_t;

#define NN 2048
#define DD 1024
#define SS 49
#define CC 1000
#define CP 1024

#define BK 64
#define KK DD
#define NT (KK / BK)   // 16 K-steps

// pool geometry: unit = 128 rows x 49 floats = 25088 B (fits the 32KB LDS cap)
#define PU_ROWS  128
#define PU_CHUNK 1568                     // 16B chunks per unit
#define N_PU     ((NN * DD) / PU_ROWS)    // 16384

__device__ inline u16 f2bf(float f) {
    __hip_bfloat16 h = __float2bfloat16(f);
    union { __hip_bfloat16 h; u16 u; } cv; cv.h = h; return cv.u;
}
__device__ inline float bf2f(u16 u) {
    union { float f; unsigned int i; } c; c.i = ((unsigned int)u) << 16; return c.f;
}

// ---- 64x64 MFMA GEMM core: 2-phase double-buffer, 32KB LDS (r3/r6 core) ----
__device__ __forceinline__ void gemm64_core(const u16* __restrict__ A,
                                            const u16* __restrict__ Bt,
                                            int m0, int n0, char* smem,
                                            f32x4 acc[2][2], int tid) {
    char* As = smem;            // [2][8192]
    char* Bs = smem + 16384;    // [2][8192]
    const int lane = tid & 63;
    const int wr = (tid >> 6) >> 1, wc = (tid >> 6) & 1;
    const int r16 = lane & 15, hk = lane >> 4;
    const char* Ab = (const char*)A;
    const char* Bb = (const char*)Bt;

    auto stage = [&](int buf, int k0) {
        #pragma unroll
        for (int j = 0; j < 2; j++) {
            const int c = j * 256 + tid;
            const int row = c >> 3, slot = c & 7;
            const int goff = ((slot ^ (row & 7)) << 4);
            __builtin_amdgcn_global_load_lds(
                (gv_t*)(Ab + ((size_t)(m0 + row) * KK + k0) * 2 + goff),
                (lv_t*)(As + buf * 8192 + c * 16), 16, 0, 0);
            __builtin_amdgcn_global_load_lds(
                (gv_t*)(Bb + ((size_t)(n0 + row) * KK + k0) * 2 + goff),
                (lv_t*)(Bs + buf * 8192 + c * 16), 16, 0, 0);
        }
    };

    stage(0, 0);
    __syncthreads();
    int cur = 0;
    for (int t = 0; t < NT; ++t) {
        if (t + 1 < NT) stage(cur ^ 1, (t + 1) * BK);
        bf16x8 a[2][2], b[2][2];
        #pragma unroll
        for (int mi = 0; mi < 2; mi++) {
            const int row = wr * 32 + mi * 16 + r16;
            #pragma unroll
            for (int kk2 = 0; kk2 < 2; kk2++) {
                const int g = kk2 * 4 + hk;
                a[mi][kk2] = *(const bf16x8*)(As + cur * 8192 + row * 128 + ((g ^ (row & 7)) << 4));
            }
        }
        #pragma unroll
        for (int ni = 0; ni < 2; ni++) {
            const int row = wc * 32 + ni * 16 + r16;
            #pragma unroll
            for (int kk2 = 0; kk2 < 2; kk2++) {
                const int g = kk2 * 4 + hk;
                b[ni][kk2] = *(const bf16x8*)(Bs + cur * 8192 + row * 128 + ((g ^ (row & 7)) << 4));
            }
        }
        #pragma unroll
        for (int kk2 = 0; kk2 < 2; kk2++)
            #pragma unroll
            for (int mi = 0; mi < 2; mi++)
                #pragma unroll
                for (int ni = 0; ni < 2; ni++)
                    acc[mi][ni] = __builtin_amdgcn_mfma_f32_16x16x32_bf16(
                        a[mi][kk2], b[ni][kk2], acc[mi][ni], 0, 0, 0);
        __syncthreads();
        cur ^= 1;
    }
}

// ---- L0: prep via LDS tile transpose (r10) ---------------------------------
__global__ __launch_bounds__(256) void prep_k(const float* __restrict__ P,
                                              const float* __restrict__ mu,
                                              u16* __restrict__ q,
                                              u16* __restrict__ mu_bf,
                                              float* __restrict__ qzh,
                                              float* __restrict__ qmuh) {
    __shared__ float t1[64][65];
    __shared__ float t2[64][65];
    const int tid = threadIdx.x, bid = blockIdx.x;
    const int br = bid >> 4, bc = bid & 15;
    const int br64 = br * 64, bc64 = bc * 64;

    #pragma unroll
    for (int it = 0; it < 16; it++) {
        const int idx = it * 256 + tid;
        const int row = idx >> 6, col = idx & 63;
        t1[row][col] = P[(size_t)(br64 + row) * DD + bc64 + col];
        t2[row][col] = P[(size_t)(bc64 + row) * DD + br64 + col];
    }
    __syncthreads();
    #pragma unroll
    for (int it = 0; it < 16; it++) {
        const int idx = it * 256 + tid;
        const int row = idx >> 6, col = idx & 63;
        q[(size_t)(br64 + row) * DD + bc64 + col] = f2bf(t1[row][col] + t2[col][row]);
    }

    const size_t base = (size_t)bid * 4096;
    #pragma unroll
    for (int it = 0; it < 16; it++) {
        const size_t j = base + it * 256 + tid;
        const int r = (int)(j >> 10);
        mu_bf[j] = f2bf(r < CC ? mu[j] : 0.f);
    }
    const int g = bid * 256 + tid;
    if (g < NN) qzh[g]  = 0.f;
    if (g < CP) qmuh[g] = 0.f;
}

// ---- L1: muQ GEMM (256 blocks, first) + pool (16384 x 128-row units) -------
// LDS capped at 32KB (gemm need; pool uses 25088 of it) -> 5 blocks/CU =
// 20 waves/CU, vs 12 at the old 50KB unit. More co-resident blocks
// desynchronize load/reduce phases -> VMEM pipe stays fed through reduces.
// Pool writes ONLY z_bf (zf f32 copy eliminated; epilogue dots use bf16 z).
__global__ __launch_bounds__(256) void pool_muq_k(const float* __restrict__ x,
                                                  const u16* __restrict__ q,
                                                  const u16* __restrict__ mu_bf,
                                                  const float* __restrict__ mu,
                                                  u16* __restrict__ b_bf,
                                                  float* __restrict__ qmuh,
                                                  u16* __restrict__ zb) {
    __shared__ char smem[32768];
    const int tid = threadIdx.x;
    const int bid = blockIdx.x;

    if (bid >= 256) {
        // ---------------- pool unit: 128 rows ----------------
        const int u = bid - 256;
        float* lds = (float*)smem;                        // 25088 B used
        const float4* src = (const float4*)(x + (size_t)u * (PU_ROWS * SS));
        float4* dst = (float4*)lds;
        #pragma unroll
        for (int i = 0; i < 7; i++) {
            int idx = i * 256 + tid;
            if (idx < PU_CHUNK) dst[idx] = src[idx];
        }
        __syncthreads();
        if (tid < PU_ROWS) {
            const float* r = lds + tid * SS;
            float s = 0.f;
            #pragma unroll
            for (int j = 0; j < SS; j++) s += r[j];
            s *= (1.f / 49.f);
            zb[(size_t)u * PU_ROWS + tid] = f2bf(s);
        }
        return;
    }

    // ---------------- muQ GEMM tile (b_bf + qmuh) ----------------
    const int m0 = (bid >> 4) * 64, n0 = (bid & 15) * 64;
    f32x4 acc[2][2] = {};
    gemm64_core(mu_bf, q, m0, n0, smem, acc, tid);

    const int lane = tid & 63;
    const int wr = (tid >> 6) >> 1, wc = (tid >> 6) & 1;
    const int cr = (lane >> 4) * 4, cc2 = lane & 15;
    #pragma unroll
    for (int mi = 0; mi < 2; mi++) {
        const int gr0 = m0 + wr * 32 + mi * 16 + cr;
        #pragma unroll
        for (int r = 0; r < 4; r++) {
            const int row = gr0 + r;
            float v = 0.f;
            #pragma unroll
            for (int ni = 0; ni < 2; ni++) {
                const int gc = n0 + wc * 32 + ni * 16 + cc2;
                float av = acc[mi][ni][r];
                float sv = (row < CC) ? mu[(size_t)row * DD + gc] : 0.f;
                v += av * sv;
                b_bf[(size_t)row * DD + gc] = f2bf(av);
            }
            #pragma unroll
            for (int m = 1; m < 16; m <<= 1) v += __shfl_xor(v, m);
            if (cc2 == 0) atomicAdd(qmuh + row, 0.25f * v);
        }
    }
}

// ---- L2: zQ-diag (bid<512) + score-partial (512) — zqd dot uses bf16 z -----
__global__ __launch_bounds__(256) void zgemm_k(const u16* __restrict__ z_bf,
                                               const u16* __restrict__ q,
                                               const u16* __restrict__ b_bf,
                                               float* __restrict__ qzh,
                                               const float* __restrict__ qmuh,
                                               float* __restrict__ out) {
    __shared__ char smem[32768];
    const int tid = threadIdx.x;
    const int bid = blockIdx.x;
    const int lane = tid & 63;
    const int wr = (tid >> 6) >> 1, wc = (tid >> 6) & 1;
    const int cr = (lane >> 4) * 4, cc2 = lane & 15;

    if (bid < 512) {
        const int m0 = (bid >> 4) * 64, n0 = (bid & 15) * 64;
        f32x4 acc[2][2] = {};
        gemm64_core(z_bf, q, m0, n0, smem, acc, tid);
        #pragma unroll
        for (int mi = 0; mi < 2; mi++) {
            const int gr0 = m0 + wr * 32 + mi * 16 + cr;
            #pragma unroll
            for (int r = 0; r < 4; r++) {
                const int row = gr0 + r;
                float v = 0.f;
                #pragma unroll
                for (int ni = 0; ni < 2; ni++) {
                    const int gc = n0 + wc * 32 + ni * 16 + cc2;
                    v += acc[mi][ni][r] * bf2f(z_bf[(size_t)row * DD + gc]);
                }
                #pragma unroll
                for (int m = 1; m < 16; m <<= 1) v += __shfl_xor(v, m);
                if (cc2 == 0) atomicAdd(qzh + row, 0.25f * v);
            }
        }
    } else {
        const int i = bid - 512;
        const int m0 = (i >> 4) * 64, n0 = (i & 15) * 64;
        f32x4 acc[2][2] = {};
        gemm64_core(z_bf, b_bf, m0, n0, smem, acc, tid);
        #pragma unroll
        for (int mi = 0; mi < 2; mi++) {
            #pragma unroll
            for (int ni = 0; ni < 2; ni++) {
                const int gr = m0 + wr * 32 + mi * 16 + cr;
                const int gc = n0 + wc * 32 + ni * 16 + cc2;
                if (gc < CC) {
                    const float qm = qmuh[gc];
                    #pragma unroll
                    for (int r = 0; r < 4; r++)
                        out[(size_t)(gr + r) * CC + gc] =
                            0.5f * acc[mi][ni][r] - qm;
                }
            }
        }
    }
}

// ---- L3: in-place fixup out[n,c] -= qzh[n] ---------------------------------
__global__ __launch_bounds__(256) void fixup_k(float* __restrict__ out,
                                               const float* __restrict__ qzh) {
    const int n = blockIdx.x, tid = threadIdx.x;
    if (tid >= 250) return;
    const float qz = qzh[n];
    float4* p = (float4*)(out + (size_t)n * CC + tid * 4);
    float4 v = *p;
    v.x -= qz; v.y -= qz; v.z -= qz; v.w -= qz;
    *p = v;
}

extern "C" void kernel_launch(void* const* d_in, const int* in_sizes, int n_in,
                              void* d_out, int out_size, void* d_ws, size_t ws_size,
                              hipStream_t stream) {
    const float* x  = (const float*)d_in[0];   // [N, D, S]
    const float* mu = (const float*)d_in[1];   // [C, D]
    const float* P  = (const float*)d_in[2];   // [D, D]
    float* out = (float*)d_out;                // [N, C]

    // workspace carve (~10.3 MB; zf eliminated)
    char* w = (char*)d_ws;
    u16*   q_bf  = (u16*)w;   w += (size_t)DD * DD * 2;   // 2 MB
    u16*   mu_bf = (u16*)w;   w += (size_t)CP * DD * 2;   // 2 MB
    u16*   b_bf  = (u16*)w;   w += (size_t)CP * DD * 2;   // 2 MB
    u16*   z_bf  = (u16*)w;   w += (size_t)NN * DD * 2;   // 4 MB
    float* qzh   = (float*)w; w += (size_t)NN * 4;
    float* qmuh  = (float*)w;

    // L0: prep (coalesced P^T via LDS transpose) + mu cast + zeroing
    prep_k<<<256, 256, 0, stream>>>(P, mu, q_bf, mu_bf, qzh, qmuh);
    // L1: muQ (256, first) + pool (16384 x 128-row units, 5 blocks/CU)
    pool_muq_k<<<256 + N_PU, 256, 0, stream>>>(
        x, q_bf, mu_bf, mu, b_bf, qmuh, z_bf);
    // L2: zQ-diag (512) + score-partial (512) -> out (minus qmuh only)
    zgemm_k<<<1024, 256, 0, stream>>>(z_bf, q_bf, b_bf, qzh, qmuh, out);
    // L3: out[n,:] -= qzh[n] in place
    fixup_k<<<NN, 256, 0, stream>>>(out, qzh);
}

// Round 15
// 116.425 us; speedup vs baseline: 3.1180x; 1.0180x over previous
//
#include <hip/hip_runtime.h>
#include <hip/hip_bf16.h>

typedef unsigned short u16;
typedef __bf16 bf16x8 __attribute__((ext_vector_type(8)));
typedef float f32x4 __attribute__((ext_vector_type(4)));

typedef const __attribute__((address_space(1))) void gv_t;
typedef __attribute__((address_space(3))) void lv_t;

#define NN 2048
#define DD 1024
#define SS 49
#define CC 1000
#define CP 1024

#define BK 64
#define KK DD
#define NT (KK / BK)   // 16 K-steps

__device__ inline u16 f2bf(float f) {
    __hip_bfloat16 h = __float2bfloat16(f);
    union { __hip_bfloat16 h; u16 u; } cv; cv.h = h; return cv.u;
}
__device__ inline float bf2f(u16 u) {
    union { float f; unsigned int i; } c; c.i = ((unsigned int)u) << 16; return c.f;
}

// ---- 64x64 MFMA GEMM core: 2-phase double-buffer, 32KB LDS (r3/r6 core) ----
__device__ __forceinline__ void gemm64_core(const u16* __restrict__ A,
                                            const u16* __restrict__ Bt,
                                            int m0, int n0, char* smem,
                                            f32x4 acc[2][2], int tid) {
    char* As = smem;            // [2][8192]
    char* Bs = smem + 16384;    // [2][8192]
    const int lane = tid & 63;
    const int wr = (tid >> 6) >> 1, wc = (tid >> 6) & 1;
    const int r16 = lane & 15, hk = lane >> 4;
    const char* Ab = (const char*)A;
    const char* Bb = (const char*)Bt;

    auto stage = [&](int buf, int k0) {
        #pragma unroll
        for (int j = 0; j < 2; j++) {
            const int c = j * 256 + tid;
            const int row = c >> 3, slot = c & 7;
            const int goff = ((slot ^ (row & 7)) << 4);
            __builtin_amdgcn_global_load_lds(
                (gv_t*)(Ab + ((size_t)(m0 + row) * KK + k0) * 2 + goff),
                (lv_t*)(As + buf * 8192 + c * 16), 16, 0, 0);
            __builtin_amdgcn_global_load_lds(
                (gv_t*)(Bb + ((size_t)(n0 + row) * KK + k0) * 2 + goff),
                (lv_t*)(Bs + buf * 8192 + c * 16), 16, 0, 0);
        }
    };

    stage(0, 0);
    __syncthreads();
    int cur = 0;
    for (int t = 0; t < NT; ++t) {
        if (t + 1 < NT) stage(cur ^ 1, (t + 1) * BK);
        bf16x8 a[2][2], b[2][2];
        #pragma unroll
        for (int mi = 0; mi < 2; mi++) {
            const int row = wr * 32 + mi * 16 + r16;
            #pragma unroll
            for (int kk2 = 0; kk2 < 2; kk2++) {
                const int g = kk2 * 4 + hk;
                a[mi][kk2] = *(const bf16x8*)(As + cur * 8192 + row * 128 + ((g ^ (row & 7)) << 4));
            }
        }
        #pragma unroll
        for (int ni = 0; ni < 2; ni++) {
            const int row = wc * 32 + ni * 16 + r16;
            #pragma unroll
            for (int kk2 = 0; kk2 < 2; kk2++) {
                const int g = kk2 * 4 + hk;
                b[ni][kk2] = *(const bf16x8*)(Bs + cur * 8192 + row * 128 + ((g ^ (row & 7)) << 4));
            }
        }
        #pragma unroll
        for (int kk2 = 0; kk2 < 2; kk2++)
            #pragma unroll
            for (int mi = 0; mi < 2; mi++)
                #pragma unroll
                for (int ni = 0; ni < 2; ni++)
                    acc[mi][ni] = __builtin_amdgcn_mfma_f32_16x16x32_bf16(
                        a[mi][kk2], b[ni][kk2], acc[mi][ni], 0, 0, 0);
        __syncthreads();
        cur ^= 1;
    }
}

// ---- L0: prep via LDS tile transpose (r10) ---------------------------------
__global__ __launch_bounds__(256) void prep_k(const float* __restrict__ P,
                                              const float* __restrict__ mu,
                                              u16* __restrict__ q,
                                              u16* __restrict__ mu_bf,
                                              float* __restrict__ qzh,
                                              float* __restrict__ qmuh) {
    __shared__ float t1[64][65];
    __shared__ float t2[64][65];
    const int tid = threadIdx.x, bid = blockIdx.x;
    const int br = bid >> 4, bc = bid & 15;
    const int br64 = br * 64, bc64 = bc * 64;

    #pragma unroll
    for (int it = 0; it < 16; it++) {
        const int idx = it * 256 + tid;
        const int row = idx >> 6, col = idx & 63;
        t1[row][col] = P[(size_t)(br64 + row) * DD + bc64 + col];
        t2[row][col] = P[(size_t)(bc64 + row) * DD + br64 + col];
    }
    __syncthreads();
    #pragma unroll
    for (int it = 0; it < 16; it++) {
        const int idx = it * 256 + tid;
        const int row = idx >> 6, col = idx & 63;
        q[(size_t)(br64 + row) * DD + bc64 + col] = f2bf(t1[row][col] + t2[col][row]);
    }

    const size_t base = (size_t)bid * 4096;
    #pragma unroll
    for (int it = 0; it < 16; it++) {
        const size_t j = base + it * 256 + tid;
        const int r = (int)(j >> 10);
        mu_bf[j] = f2bf(r < CC ? mu[j] : 0.f);
    }
    const int g = bid * 256 + tid;
    if (g < NN) qzh[g]  = 0.f;
    if (g < CP) qmuh[g] = 0.f;
}

// ---- L1: muQ GEMM (256 blocks, first) + DIRECT-READ pool (8192 blocks) -----
// Pool: one thread per 49-float row, 12 float4 (+1 scalar) register sums.
// No LDS, no __syncthreads, no idle lanes. Wave window = 64 rows x 196B =
// 12.3KB -> first-iteration miss storm fetches each 64B line once (all bytes
// used -> HBM-efficient), iterations 1..12 hit L1. memcpy emits legal
// (possibly unaligned) 16B loads.
__global__ __launch_bounds__(256) void pool_muq_k(const float* __restrict__ x,
                                                  const u16* __restrict__ q,
                                                  const u16* __restrict__ mu_bf,
                                                  const float* __restrict__ mu,
                                                  u16* __restrict__ b_bf,
                                                  float* __restrict__ qmuh,
                                                  u16* __restrict__ zb) {
    __shared__ char smem[32768];
    const int tid = threadIdx.x;
    const int bid = blockIdx.x;

    if (bid >= 256) {
        const size_t row = (size_t)(bid - 256) * 256 + tid;   // (n,d) row id
        const float* r = x + row * SS;
        float4 s4 = {0.f, 0.f, 0.f, 0.f};
        #pragma unroll
        for (int i = 0; i < 12; i++) {
            float4 v;
            __builtin_memcpy(&v, r + 4 * i, 16);
            s4.x += v.x; s4.y += v.y; s4.z += v.z; s4.w += v.w;
        }
        const float s = (s4.x + s4.y + s4.z + s4.w + r[48]) * (1.f / 49.f);
        zb[row] = f2bf(s);
        return;
    }

    // ---------------- muQ GEMM tile (b_bf + qmuh) ----------------
    const int m0 = (bid >> 4) * 64, n0 = (bid & 15) * 64;
    f32x4 acc[2][2] = {};
    gemm64_core(mu_bf, q, m0, n0, smem, acc, tid);

    const int lane = tid & 63;
    const int wr = (tid >> 6) >> 1, wc = (tid >> 6) & 1;
    const int cr = (lane >> 4) * 4, cc2 = lane & 15;
    #pragma unroll
    for (int mi = 0; mi < 2; mi++) {
        const int gr0 = m0 + wr * 32 + mi * 16 + cr;
        #pragma unroll
        for (int r = 0; r < 4; r++) {
            const int row = gr0 + r;
            float v = 0.f;
            #pragma unroll
            for (int ni = 0; ni < 2; ni++) {
                const int gc = n0 + wc * 32 + ni * 16 + cc2;
                float av = acc[mi][ni][r];
                float sv = (row < CC) ? mu[(size_t)row * DD + gc] : 0.f;
                v += av * sv;
                b_bf[(size_t)row * DD + gc] = f2bf(av);
            }
            #pragma unroll
            for (int m = 1; m < 16; m <<= 1) v += __shfl_xor(v, m);
            if (cc2 == 0) atomicAdd(qmuh + row, 0.25f * v);
        }
    }
}

// ---- L2: zQ-diag (bid<512) + score-partial (512) — r14 verbatim ------------
__global__ __launch_bounds__(256) void zgemm_k(const u16* __restrict__ z_bf,
                                               const u16* __restrict__ q,
                                               const u16* __restrict__ b_bf,
                                               float* __restrict__ qzh,
                                               const float* __restrict__ qmuh,
                                               float* __restrict__ out) {
    __shared__ char smem[32768];
    const int tid = threadIdx.x;
    const int bid = blockIdx.x;
    const int lane = tid & 63;
    const int wr = (tid >> 6) >> 1, wc = (tid >> 6) & 1;
    const int cr = (lane >> 4) * 4, cc2 = lane & 15;

    if (bid < 512) {
        const int m0 = (bid >> 4) * 64, n0 = (bid & 15) * 64;
        f32x4 acc[2][2] = {};
        gemm64_core(z_bf, q, m0, n0, smem, acc, tid);
        #pragma unroll
        for (int mi = 0; mi < 2; mi++) {
            const int gr0 = m0 + wr * 32 + mi * 16 + cr;
            #pragma unroll
            for (int r = 0; r < 4; r++) {
                const int row = gr0 + r;
                float v = 0.f;
                #pragma unroll
                for (int ni = 0; ni < 2; ni++) {
                    const int gc = n0 + wc * 32 + ni * 16 + cc2;
                    v += acc[mi][ni][r] * bf2f(z_bf[(size_t)row * DD + gc]);
                }
                #pragma unroll
                for (int m = 1; m < 16; m <<= 1) v += __shfl_xor(v, m);
                if (cc2 == 0) atomicAdd(qzh + row, 0.25f * v);
            }
        }
    } else {
        const int i = bid - 512;
        const int m0 = (i >> 4) * 64, n0 = (i & 15) * 64;
        f32x4 acc[2][2] = {};
        gemm64_core(z_bf, b_bf, m0, n0, smem, acc, tid);
        #pragma unroll
        for (int mi = 0; mi < 2; mi++) {
            #pragma unroll
            for (int ni = 0; ni < 2; ni++) {
                const int gr = m0 + wr * 32 + mi * 16 + cr;
                const int gc = n0 + wc * 32 + ni * 16 + cc2;
                if (gc < CC) {
                    const float qm = qmuh[gc];
                    #pragma unroll
                    for (int r = 0; r < 4; r++)
                        out[(size_t)(gr + r) * CC + gc] =
                            0.5f * acc[mi][ni][r] - qm;
                }
            }
        }
    }
}

// ---- L3: in-place fixup out[n,c] -= qzh[n] ---------------------------------
__global__ __launch_bounds__(256) void fixup_k(float* __restrict__ out,
                                               const float* __restrict__ qzh) {
    const int n = blockIdx.x, tid = threadIdx.x;
    if (tid >= 250) return;
    const float qz = qzh[n];
    float4* p = (float4*)(out + (size_t)n * CC + tid * 4);
    float4 v = *p;
    v.x -= qz; v.y -= qz; v.z -= qz; v.w -= qz;
    *p = v;
}

extern "C" void kernel_launch(void* const* d_in, const int* in_sizes, int n_in,
                              void* d_out, int out_size, void* d_ws, size_t ws_size,
                              hipStream_t stream) {
    const float* x  = (const float*)d_in[0];   // [N, D, S]
    const float* mu = (const float*)d_in[1];   // [C, D]
    const float* P  = (const float*)d_in[2];   // [D, D]
    float* out = (float*)d_out;                // [N, C]

    // workspace carve (~10.3 MB)
    char* w = (char*)d_ws;
    u16*   q_bf  = (u16*)w;   w += (size_t)DD * DD * 2;   // 2 MB
    u16*   mu_bf = (u16*)w;   w += (size_t)CP * DD * 2;   // 2 MB
    u16*   b_bf  = (u16*)w;   w += (size_t)CP * DD * 2;   // 2 MB
    u16*   z_bf  = (u16*)w;   w += (size_t)NN * DD * 2;   // 4 MB
    float* qzh   = (float*)w; w += (size_t)NN * 4;
    float* qmuh  = (float*)w;

    // L0: prep (coalesced P^T via LDS transpose) + mu cast + zeroing
    prep_k<<<256, 256, 0, stream>>>(P, mu, q_bf, mu_bf, qzh, qmuh);
    // L1: muQ (256, first) + direct-read pool (8192, 1 row/thread, no LDS)
    pool_muq_k<<<256 + (NN * DD) / 256, 256, 0, stream>>>(
        x, q_bf, mu_bf, mu, b_bf, qmuh, z_bf);
    // L2: zQ-diag (512) + score-partial (512) -> out (minus qmuh only)
    zgemm_k<<<1024, 256, 0, stream>>>(z_bf, q_bf, b_bf, qzh, qmuh, out);
    // L3: out[n,:] -= qzh[n] in place
    fixup_k<<<NN, 256, 0, stream>>>(out, qzh);
}

// Round 16
// 116.403 us; speedup vs baseline: 3.1186x; 1.0002x over previous
//
#include <hip/hip_runtime.h>
#include <hip/hip_bf16.h>

typedef unsigned short u16;
typedef __bf16 bf16x8 __attribute__((ext_vector_type(8)));
typedef float f32x4 __attribute__((ext_vector_type(4)));

typedef const __attribute__((address_space(1))) void gv_t;
typedef __attribute__((address_space(3))) void lv_t;

#define NN 2048
#define DD 1024
#define SS 49
#define CC 1000
#define CP 1024

#define BK 64
#define KK DD
#define NT (KK / BK)   // 16 K-steps

#define HEAD_PU 512    // pool units in the head launch (covers prep's ~3us)

__device__ inline u16 f2bf(float f) {
    __hip_bfloat16 h = __float2bfloat16(f);
    union { __hip_bfloat16 h; u16 u; } cv; cv.h = h; return cv.u;
}
__device__ inline float bf2f(u16 u) {
    union { float f; unsigned int i; } c; c.i = ((unsigned int)u) << 16; return c.f;
}

// ---- direct-read pool unit (r15): one thread per 49-float row --------------
__device__ __forceinline__ void pool_rows(const float* __restrict__ x,
                                          u16* __restrict__ zb,
                                          size_t row) {
    const float* r = x + row * SS;
    float4 s4 = {0.f, 0.f, 0.f, 0.f};
    #pragma unroll
    for (int i = 0; i < 12; i++) {
        float4 v;
        __builtin_memcpy(&v, r + 4 * i, 16);
        s4.x += v.x; s4.y += v.y; s4.z += v.z; s4.w += v.w;
    }
    const float s = (s4.x + s4.y + s4.z + s4.w + r[48]) * (1.f / 49.f);
    zb[row] = f2bf(s);
}

// ---- 64x64 MFMA GEMM core: 2-phase double-buffer, 32KB LDS (r3/r6 core) ----
__device__ __forceinline__ void gemm64_core(const u16* __restrict__ A,
                                            const u16* __restrict__ Bt,
                                            int m0, int n0, char* smem,
                                            f32x4 acc[2][2], int tid) {
    char* As = smem;            // [2][8192]
    char* Bs = smem + 16384;    // [2][8192]
    const int lane = tid & 63;
    const int wr = (tid >> 6) >> 1, wc = (tid >> 6) & 1;
    const int r16 = lane & 15, hk = lane >> 4;
    const char* Ab = (const char*)A;
    const char* Bb = (const char*)Bt;

    auto stage = [&](int buf, int k0) {
        #pragma unroll
        for (int j = 0; j < 2; j++) {
            const int c = j * 256 + tid;
            const int row = c >> 3, slot = c & 7;
            const int goff = ((slot ^ (row & 7)) << 4);
            __builtin_amdgcn_global_load_lds(
                (gv_t*)(Ab + ((size_t)(m0 + row) * KK + k0) * 2 + goff),
                (lv_t*)(As + buf * 8192 + c * 16), 16, 0, 0);
            __builtin_amdgcn_global_load_lds(
                (gv_t*)(Bb + ((size_t)(n0 + row) * KK + k0) * 2 + goff),
                (lv_t*)(Bs + buf * 8192 + c * 16), 16, 0, 0);
        }
    };

    stage(0, 0);
    __syncthreads();
    int cur = 0;
    for (int t = 0; t < NT; ++t) {
        if (t + 1 < NT) stage(cur ^ 1, (t + 1) * BK);
        bf16x8 a[2][2], b[2][2];
        #pragma unroll
        for (int mi = 0; mi < 2; mi++) {
            const int row = wr * 32 + mi * 16 + r16;
            #pragma unroll
            for (int kk2 = 0; kk2 < 2; kk2++) {
                const int g = kk2 * 4 + hk;
                a[mi][kk2] = *(const bf16x8*)(As + cur * 8192 + row * 128 + ((g ^ (row & 7)) << 4));
            }
        }
        #pragma unroll
        for (int ni = 0; ni < 2; ni++) {
            const int row = wc * 32 + ni * 16 + r16;
            #pragma unroll
            for (int kk2 = 0; kk2 < 2; kk2++) {
                const int g = kk2 * 4 + hk;
                b[ni][kk2] = *(const bf16x8*)(Bs + cur * 8192 + row * 128 + ((g ^ (row & 7)) << 4));
            }
        }
        #pragma unroll
        for (int kk2 = 0; kk2 < 2; kk2++)
            #pragma unroll
            for (int mi = 0; mi < 2; mi++)
                #pragma unroll
                for (int ni = 0; ni < 2; ni++)
                    acc[mi][ni] = __builtin_amdgcn_mfma_f32_16x16x32_bf16(
                        a[mi][kk2], b[ni][kk2], acc[mi][ni], 0, 0, 0);
        __syncthreads();
        cur ^= 1;
    }
}

// ---- L0': prep (256 blocks) + pool head slice (HEAD_PU blocks) -------------
// prep = r10's LDS tile transpose (coalesced P^T). Pool head is independent
// of prep -> prep's ~3us hides under the slice's streaming.
__global__ __launch_bounds__(256) void prep_pool_k(const float* __restrict__ P,
                                                   const float* __restrict__ mu,
                                                   const float* __restrict__ x,
                                                   u16* __restrict__ q,
                                                   u16* __restrict__ mu_bf,
                                                   u16* __restrict__ zb,
                                                   float* __restrict__ qzh,
                                                   float* __restrict__ qmuh) {
    __shared__ float t1[64][65];
    __shared__ float t2[64][65];
    const int tid = threadIdx.x, bid = blockIdx.x;

    if (bid >= 256) {   // pool head: rows [0, HEAD_PU*256)
        pool_rows(x, zb, (size_t)(bid - 256) * 256 + tid);
        return;
    }

    const int br = bid >> 4, bc = bid & 15;
    const int br64 = br * 64, bc64 = bc * 64;
    #pragma unroll
    for (int it = 0; it < 16; it++) {
        const int idx = it * 256 + tid;
        const int row = idx >> 6, col = idx & 63;
        t1[row][col] = P[(size_t)(br64 + row) * DD + bc64 + col];
        t2[row][col] = P[(size_t)(bc64 + row) * DD + br64 + col];
    }
    __syncthreads();
    #pragma unroll
    for (int it = 0; it < 16; it++) {
        const int idx = it * 256 + tid;
        const int row = idx >> 6, col = idx & 63;
        q[(size_t)(br64 + row) * DD + bc64 + col] = f2bf(t1[row][col] + t2[col][row]);
    }

    const size_t base = (size_t)bid * 4096;
    #pragma unroll
    for (int it = 0; it < 16; it++) {
        const size_t j = base + it * 256 + tid;
        const int r = (int)(j >> 10);
        mu_bf[j] = f2bf(r < CC ? mu[j] : 0.f);
    }
    const int g = bid * 256 + tid;
    if (g < NN) qzh[g]  = 0.f;
    if (g < CP) qmuh[g] = 0.f;
}

// ---- L1': muQ GEMM (256 blocks, first) + pool rest (7680 blocks) -----------
__global__ __launch_bounds__(256) void pool_muq_k(const float* __restrict__ x,
                                                  const u16* __restrict__ q,
                                                  const u16* __restrict__ mu_bf,
                                                  const float* __restrict__ mu,
                                                  u16* __restrict__ b_bf,
                                                  float* __restrict__ qmuh,
                                                  u16* __restrict__ zb) {
    __shared__ char smem[32768];
    const int tid = threadIdx.x;
    const int bid = blockIdx.x;

    if (bid >= 256) {   // pool rows [HEAD_PU*256, 8192*256)
        pool_rows(x, zb, (size_t)(bid - 256 + HEAD_PU) * 256 + tid);
        return;
    }

    // ---------------- muQ GEMM tile (b_bf + qmuh) ----------------
    const int m0 = (bid >> 4) * 64, n0 = (bid & 15) * 64;
    f32x4 acc[2][2] = {};
    gemm64_core(mu_bf, q, m0, n0, smem, acc, tid);

    const int lane = tid & 63;
    const int wr = (tid >> 6) >> 1, wc = (tid >> 6) & 1;
    const int cr = (lane >> 4) * 4, cc2 = lane & 15;
    #pragma unroll
    for (int mi = 0; mi < 2; mi++) {
        const int gr0 = m0 + wr * 32 + mi * 16 + cr;
        #pragma unroll
        for (int r = 0; r < 4; r++) {
            const int row = gr0 + r;
            float v = 0.f;
            #pragma unroll
            for (int ni = 0; ni < 2; ni++) {
                const int gc = n0 + wc * 32 + ni * 16 + cc2;
                float av = acc[mi][ni][r];
                float sv = (row < CC) ? mu[(size_t)row * DD + gc] : 0.f;
                v += av * sv;
                b_bf[(size_t)row * DD + gc] = f2bf(av);
            }
            #pragma unroll
            for (int m = 1; m < 16; m <<= 1) v += __shfl_xor(v, m);
            if (cc2 == 0) atomicAdd(qmuh + row, 0.25f * v);
        }
    }
}

// ---- L2: zQ-diag (bid<512) + score-partial (512) — r14/r15 verbatim --------
__global__ __launch_bounds__(256) void zgemm_k(const u16* __restrict__ z_bf,
                                               const u16* __restrict__ q,
                                               const u16* __restrict__ b_bf,
                                               float* __restrict__ qzh,
                                               const float* __restrict__ qmuh,
                                               float* __restrict__ out) {
    __shared__ char smem[32768];
    const int tid = threadIdx.x;
    const int bid = blockIdx.x;
    const int lane = tid & 63;
    const int wr = (tid >> 6) >> 1, wc = (tid >> 6) & 1;
    const int cr = (lane >> 4) * 4, cc2 = lane & 15;

    if (bid < 512) {
        const int m0 = (bid >> 4) * 64, n0 = (bid & 15) * 64;
        f32x4 acc[2][2] = {};
        gemm64_core(z_bf, q, m0, n0, smem, acc, tid);
        #pragma unroll
        for (int mi = 0; mi < 2; mi++) {
            const int gr0 = m0 + wr * 32 + mi * 16 + cr;
            #pragma unroll
            for (int r = 0; r < 4; r++) {
                const int row = gr0 + r;
                float v = 0.f;
                #pragma unroll
                for (int ni = 0; ni < 2; ni++) {
                    const int gc = n0 + wc * 32 + ni * 16 + cc2;
                    v += acc[mi][ni][r] * bf2f(z_bf[(size_t)row * DD + gc]);
                }
                #pragma unroll
                for (int m = 1; m < 16; m <<= 1) v += __shfl_xor(v, m);
                if (cc2 == 0) atomicAdd(qzh + row, 0.25f * v);
            }
        }
    } else {
        const int i = bid - 512;
        const int m0 = (i >> 4) * 64, n0 = (i & 15) * 64;
        f32x4 acc[2][2] = {};
        gemm64_core(z_bf, b_bf, m0, n0, smem, acc, tid);
        #pragma unroll
        for (int mi = 0; mi < 2; mi++) {
            #pragma unroll
            for (int ni = 0; ni < 2; ni++) {
                const int gr = m0 + wr * 32 + mi * 16 + cr;
                const int gc = n0 + wc * 32 + ni * 16 + cc2;
                if (gc < CC) {
                    const float qm = qmuh[gc];
                    #pragma unroll
                    for (int r = 0; r < 4; r++)
                        out[(size_t)(gr + r) * CC + gc] =
                            0.5f * acc[mi][ni][r] - qm;
                }
            }
        }
    }
}

// ---- L3: in-place fixup out[n,c] -= qzh[n] ---------------------------------
__global__ __launch_bounds__(256) void fixup_k(float* __restrict__ out,
                                               const float* __restrict__ qzh) {
    const int n = blockIdx.x, tid = threadIdx.x;
    if (tid >= 250) return;
    const float qz = qzh[n];
    float4* p = (float4*)(out + (size_t)n * CC + tid * 4);
    float4 v = *p;
    v.x -= qz; v.y -= qz; v.z -= qz; v.w -= qz;
    *p = v;
}

extern "C" void kernel_launch(void* const* d_in, const int* in_sizes, int n_in,
                              void* d_out, int out_size, void* d_ws, size_t ws_size,
                              hipStream_t stream) {
    const float* x  = (const float*)d_in[0];   // [N, D, S]
    const float* mu = (const float*)d_in[1];   // [C, D]
    const float* P  = (const float*)d_in[2];   // [D, D]
    float* out = (float*)d_out;                // [N, C]

    // workspace carve (~10.3 MB)
    char* w = (char*)d_ws;
    u16*   q_bf  = (u16*)w;   w += (size_t)DD * DD * 2;   // 2 MB
    u16*   mu_bf = (u16*)w;   w += (size_t)CP * DD * 2;   // 2 MB
    u16*   b_bf  = (u16*)w;   w += (size_t)CP * DD * 2;   // 2 MB
    u16*   z_bf  = (u16*)w;   w += (size_t)NN * DD * 2;   // 4 MB
    float* qzh   = (float*)w; w += (size_t)NN * 4;
    float* qmuh  = (float*)w;

    // L0': prep (256, hidden) + pool head slice (512 units)
    prep_pool_k<<<256 + HEAD_PU, 256, 0, stream>>>(
        P, mu, x, q_bf, mu_bf, z_bf, qzh, qmuh);
    // L1': muQ (256, first) + pool rest (7680 units)
    pool_muq_k<<<256 + (NN * DD) / 256 - HEAD_PU, 256, 0, stream>>>(
        x, q_bf, mu_bf, mu, b_bf, qmuh, z_bf);
    // L2: zQ-diag (512) + score-partial (512) -> out (minus qmuh only)
    zgemm_k<<<1024, 256, 0, stream>>>(z_bf, q_bf, b_bf, qzh, qmuh, out);
    // L3: out[n,:] -= qzh[n] in place
    fixup_k<<<NN, 256, 0, stream>>>(out, qzh);
}